// Round 5
// baseline (2654.740 us; speedup 1.0000x reference)
//
#include <hip/hip_runtime.h>
#include <stdint.h>

#define NIMG 8
#define HFW  64
#define HWA  36864     // 64*64*9
#define PRE  2000
#define POST 300

#define AS1 __attribute__((address_space(1)))
#define AS3 __attribute__((address_space(3)))

__device__ __forceinline__ unsigned keyOf(float f) {
    unsigned u = __float_as_uint(f);
    return (u & 0x80000000u) ? ~u : (u | 0x80000000u);
}
__device__ __forceinline__ unsigned umin2(unsigned a, unsigned b){ return a < b ? a : b; }

// ---------------------------------------------------------------------------
// K0: w_conv [co][ci][3][3] -> wt3 [(ci*3+ky)*64 + co/4][ (co&3)*3 + kx ]
// ---------------------------------------------------------------------------
__global__ void prep_wt3(const float* __restrict__ w, float* __restrict__ wt3) {
    int t = blockIdx.x * 256 + threadIdx.x;      // t = (ci*3+ky)*256 + co
    if (t >= 256 * 3 * 256) return;
    int co = t & 255;
    int r  = t >> 8;            // ci*3+ky
    int ky = r % 3, ci = r / 3;
    const float* s = w + ((size_t)(co * 256 + ci)) * 9 + ky * 3;
    float* d = wt3 + ((size_t)((ci * 3 + ky) * 64 + (co >> 2))) * 12 + (co & 3) * 3;
    d[0] = s[0]; d[1] = s[1]; d[2] = s[2];
}

// ---------------------------------------------------------------------------
// K1 v5: 3x3 conv SAME + bias + relu.  fp32 VALU, scalar weights (SGPR),
// global_load_lds staging, XCD-pinned, FULL occupancy: 2048 blocks x 256thr,
// 19.6KB LDS -> 8 blocks/CU x 4 waves = 32 waves/CU.
// thread tile: 4co x 4px; block tile: 4co x 16rows x 64px; CK=2 ci/step.
// ---------------------------------------------------------------------------
__global__ __launch_bounds__(256, 8) void conv3x3_relu_v5(const float* __restrict__ feat,
        const float* __restrict__ wt3, const float* __restrict__ bconv,
        float* __restrict__ h)
{
    __shared__ __align__(16) float sAll[2 * 2 * 18 * 68];   // 19,584 B

    const int tid  = threadIdx.x;
    const int lane = tid & 63;
    const int wv   = tid >> 6;          // wave 0..3
    const int b    = blockIdx.x;
    const int n    = b & 7;             // XCD-pinned image
    const int rem  = b >> 3;
    const int cog  = rem & 63;          // 0..63  (4 co each)
    const int y0   = (rem >> 6) << 4;   // 0,16,32,48
    const int pg   = tid & 15;
    const int px   = pg * 4;
    const int rr   = tid >> 4;          // 0..15 output row in strip

    const float* fb = feat + (size_t)n * 1048576;

    // zero both buffers once (halo cols + boundary rows rely on this persisting)
    {
        const float4 z4 = {0.f, 0.f, 0.f, 0.f};
        for (int i = tid * 4; i < 4896; i += 1024) *(float4*)&sAll[i] = z4;
    }
    __syncthreads();

    float acc[4][4];
#pragma unroll
    for (int a = 0; a < 4; a++)
#pragma unroll
        for (int c = 0; c < 4; c++) acc[a][c] = 0.0f;

    // staging: 2 ci slices x 18 rows = 36 wave-loads, 9 per wave.
    // wave w: slice i = w>>1, rows r0 = (w&1)*9 + q (q=0..8).
    const int sl_i = wv >> 1;
    const int sl_r = (wv & 1) * 9;
#define ISSUE_CK(CK, BUF) {                                                  \
        const float* _gb = fb + (size_t)((CK) * 2 + sl_i) * 4096 + lane;     \
        float* _lb = (BUF) + (sl_i * 18 + sl_r) * 68 + 1;                    \
        _Pragma("unroll")                                                    \
        for (int _q = 0; _q < 9; _q++) {                                     \
            const int _gy = y0 - 1 + sl_r + _q;                              \
            if (_gy >= 0 && _gy < 64)                                        \
                __builtin_amdgcn_global_load_lds(                            \
                    (const AS1 void*)(_gb + _gy * 64),                       \
                    (AS3 void*)(_lb + _q * 68), 4, 0, 0);                    \
        } }

    ISSUE_CK(0, sAll);
    asm volatile("s_waitcnt vmcnt(0)" ::: "memory");
    __syncthreads();

    for (int ck = 0; ck < 128; ck++) {
        const int ci0 = ck * 2;
        const float* bufc = sAll + (ck & 1) * 2448;
        float*       bufn = sAll + ((ck + 1) & 1) * 2448;

        if (ck < 127) ISSUE_CK(ck + 1, bufn);

        // compute: 6 (i,ky) steps x (ds_read_b128 + ds_read_b64 + 12 scalar w + 48 fmac)
        const float* rbase = bufc + rr * 68 + px;
#pragma unroll
        for (int i = 0; i < 2; i++) {
#pragma unroll
            for (int ky = 0; ky < 3; ky++) {
                const float* rowp = rbase + (i * 18 + ky) * 68;
                const float4 fA = *(const float4*)rowp;        // cols px-1..px+2
                const float2 fB = *(const float2*)(rowp + 4);  // cols px+3..px+4
                const float fc0 = fA.x, fc1 = fA.y, fc2 = fA.z, fc3 = fA.w;
                const float fc4 = fB.x, fc5 = fB.y;
                const float* wq = wt3 + (size_t)(((ci0 + i) * 3 + ky) * 64 + cog) * 12;
#pragma unroll
                for (int cc = 0; cc < 4; cc++) {
                    const float w0 = wq[cc * 3 + 0], w1 = wq[cc * 3 + 1], w2 = wq[cc * 3 + 2];
                    acc[cc][0] = fmaf(w0, fc0, acc[cc][0]);
                    acc[cc][0] = fmaf(w1, fc1, acc[cc][0]);
                    acc[cc][0] = fmaf(w2, fc2, acc[cc][0]);
                    acc[cc][1] = fmaf(w0, fc1, acc[cc][1]);
                    acc[cc][1] = fmaf(w1, fc2, acc[cc][1]);
                    acc[cc][1] = fmaf(w2, fc3, acc[cc][1]);
                    acc[cc][2] = fmaf(w0, fc2, acc[cc][2]);
                    acc[cc][2] = fmaf(w1, fc3, acc[cc][2]);
                    acc[cc][2] = fmaf(w2, fc4, acc[cc][2]);
                    acc[cc][3] = fmaf(w0, fc3, acc[cc][3]);
                    acc[cc][3] = fmaf(w1, fc4, acc[cc][3]);
                    acc[cc][3] = fmaf(w2, fc5, acc[cc][3]);
                }
            }
        }

        asm volatile("s_waitcnt vmcnt(0)" ::: "memory");
        __syncthreads();
    }
#undef ISSUE_CK

    // epilogue: bias + relu + store
#pragma unroll
    for (int cc = 0; cc < 4; cc++) {
        const int co = cog * 4 + cc;
        const float bb = bconv[co];
        float4 o;
        o.x = fmaxf(acc[cc][0] + bb, 0.f);
        o.y = fmaxf(acc[cc][1] + bb, 0.f);
        o.z = fmaxf(acc[cc][2] + bb, 0.f);
        o.w = fmaxf(acc[cc][3] + bb, 0.f);
        *(float4*)(h + ((size_t)(n * 256 + co)) * 4096 + (y0 + rr) * 64 + px) = o;
    }
}

// ---------------------------------------------------------------------------
// K2: 1x1 heads (scores 9, locs 36) + box decode + clip + validity -> keys/rois
// ---------------------------------------------------------------------------
__global__ __launch_bounds__(256) void head_decode(const float* __restrict__ h,
        const float* __restrict__ wsc, const float* __restrict__ bsc,
        const float* __restrict__ wlc, const float* __restrict__ blc,
        unsigned* __restrict__ keys, float* __restrict__ rois)
{
    __shared__ float sH[128][64];
    __shared__ float sOut[64][49];

    const int tid = threadIdx.x;
    const int n   = blockIdx.x & 7;
    const int y   = blockIdx.x >> 3;
    const int px  = tid & 63;
    const int sl  = tid >> 6;             // == wave id
    const int o0  = sl * 12;

    const float* wp[12];
#pragma unroll
    for (int j = 0; j < 12; j++) {
        const int o = o0 + j;
        wp[j] = (o < 36) ? (wlc + (size_t)o * 256)
                         : ((o < 45) ? (wsc + (size_t)(o - 36) * 256) : wsc);
    }
    float r[12];
#pragma unroll
    for (int j = 0; j < 12; j++) r[j] = 0.0f;

    const float* hb = h + (size_t)n * 1048576 + y * 64;
    for (int half = 0; half < 2; half++) {
        for (int task = tid; task < 2048; task += 256) {
            const int c = task >> 4, x4 = (task & 15) << 2;
            *(float4*)&sH[c][x4] =
                *(const float4*)(hb + (size_t)(half * 128 + c) * 4096 + x4);
        }
        __syncthreads();
        for (int c4 = 0; c4 < 128; c4 += 4) {
            const float h0 = sH[c4][px], h1 = sH[c4 + 1][px];
            const float h2 = sH[c4 + 2][px], h3 = sH[c4 + 3][px];
#pragma unroll
            for (int j = 0; j < 12; j++) {
                float4 w = *(const float4*)(wp[j] + half * 128 + c4);
                r[j] = fmaf(h0, w.x, r[j]); r[j] = fmaf(h1, w.y, r[j]);
                r[j] = fmaf(h2, w.z, r[j]); r[j] = fmaf(h3, w.w, r[j]);
            }
        }
        __syncthreads();
    }
#pragma unroll
    for (int j = 0; j < 12; j++) {
        const int o = o0 + j;
        if (o < 45) {
            const float bias = (o < 36) ? blc[o] : bsc[o - 36];
            sOut[px][o] = r[j] + bias;
        }
    }
    __syncthreads();

    // decode (replicate reference fp32 op order; no contraction)
    for (int a = sl; a < 9; a += 4) {
        const float s  = sOut[px][36 + a];
        const float dy = sOut[px][a * 4 + 0], dx = sOut[px][a * 4 + 1];
        const float dh = sOut[px][a * 4 + 2], dw = sOut[px][a * 4 + 3];
        const int si = a / 3, ri = a - si * 3;
        const float scale = (si == 0) ? 64.f : ((si == 1) ? 128.f : 256.f);
        const float rat   = (ri == 0) ? 0.5f : ((ri == 1) ? 1.f : 2.f);
        const float sq = __fsqrt_rn(rat);
        const float hs = __fmul_rn(scale, sq);
        const float ws = __fdiv_rn(scale, sq);
        const float cy = (y  + 0.5f) * 16.0f;   // exact
        const float cx = (px + 0.5f) * 16.0f;
        const float y1 = __fsub_rn(cy, __fmul_rn(hs, 0.5f));
        const float x1 = __fsub_rn(cx, __fmul_rn(ws, 0.5f));
        const float y2 = __fadd_rn(cy, __fmul_rn(hs, 0.5f));
        const float x2 = __fadd_rn(cx, __fmul_rn(ws, 0.5f));
        const float ah = __fsub_rn(y2, y1), aw = __fsub_rn(x2, x1);
        const float acy = __fadd_rn(y1, __fmul_rn(0.5f, ah));
        const float acx = __fadd_rn(x1, __fmul_rn(0.5f, aw));
        const float pcy = __fadd_rn(__fmul_rn(dy, ah), acy);
        const float pcx = __fadd_rn(__fmul_rn(dx, aw), acx);
        const float ph  = __fmul_rn(expf(dh), ah);
        const float pw  = __fmul_rn(expf(dw), aw);
        float by1 = __fsub_rn(pcy, __fmul_rn(0.5f, ph));
        float bx1 = __fsub_rn(pcx, __fmul_rn(0.5f, pw));
        float by2 = __fadd_rn(pcy, __fmul_rn(0.5f, ph));
        float bx2 = __fadd_rn(pcx, __fmul_rn(0.5f, pw));
        by1 = fminf(fmaxf(by1, 0.f), 1024.f); by2 = fminf(fmaxf(by2, 0.f), 1024.f);
        bx1 = fminf(fmaxf(bx1, 0.f), 1024.f); bx2 = fminf(fmaxf(bx2, 0.f), 1024.f);
        const float bh = __fsub_rn(by2, by1), bw = __fsub_rn(bx2, bx1);
        const bool valid = (bh >= 16.f) && (bw >= 16.f) && (s >= 0.f);
        const float sm = valid ? s : -1e9f;
        const int idx = (y * 64 + px) * 9 + a;
        keys[(size_t)n * HWA + idx] = keyOf(sm);
        float4 bxv = {by1, bx1, by2, bx2};
        *(float4*)&rois[((size_t)n * HWA + idx) * 4] = bxv;
    }
}

// ---------------------------------------------------------------------------
// K3: FUSED exact top-2000 select + sort + greedy NMS + output.
// 1 block (1024 thr) per image.  Greedy phase = single wave, zero barriers.
// ---------------------------------------------------------------------------
__global__ __launch_bounds__(1024) void topk_nms(const unsigned* __restrict__ keys,
        const float* __restrict__ rois, float* __restrict__ out)
{
    __shared__ unsigned long long s64[2048];     // 16 KB; aliased as 2x u32[2048]
    __shared__ float sy1[2048], sx1[2048], sy2[2048], sx2[2048];  // 32 KB SoA
    __shared__ unsigned long long lwS[32];       // live bitmask (2048 bits)
    __shared__ unsigned sc[2];
    __shared__ unsigned cntG, cntE;
    unsigned* histA = (unsigned*)&s64[0];
    unsigned* histB = histA + 2048;

    const int tid  = threadIdx.x;
    const int lane = tid & 63;
    const int n    = blockIdx.x;
    const unsigned* kp = keys + (size_t)n * HWA;
    const uint4* kp4 = (const uint4*)kp;
    const unsigned KNEG = keyOf(-1e9f);

    if (n == 0 && tid == 0) out[9600] = 0.0f;   // rpn_loss

    unsigned need = PRE;
    unsigned b1 = 0, b2 = 0;

    for (int lvl = 0; lvl < 3; lvl++) {
        for (int i = tid; i < 2048; i += 1024) histA[i] = 0u;
        if (tid == 0) { cntG = 0u; cntE = 0u; }
        __syncthreads();
        for (int i = tid; i < 9216; i += 1024) {
            const uint4 kv = kp4[i];
#pragma unroll
            for (int c = 0; c < 4; c++) {
                const unsigned k = (&kv.x)[c];
                if (lvl == 0) {
                    // wave-aggregate the massive -1e9 class (~half of all keys)
                    const bool ineg = (k == KNEG);
                    const unsigned long long mn = __ballot(ineg);
                    if (ineg) {
                        if (lane == __ffsll((long long)mn) - 1)
                            atomicAdd(&histA[KNEG >> 21], (unsigned)__popcll(mn));
                    } else {
                        atomicAdd(&histA[k >> 21], 1u);
                    }
                } else if (lvl == 1) {
                    if ((k >> 21) == b1) atomicAdd(&histA[(k >> 10) & 2047u], 1u);
                } else {
                    if ((k >> 10) == ((b1 << 11) | b2)) atomicAdd(&histA[k & 1023u], 1u);
                }
            }
        }
        __syncthreads();
        unsigned *src = histA, *dst = histB;
        for (int ofs = 1; ofs < 2048; ofs <<= 1) {
            for (int i = tid; i < 2048; i += 1024)
                dst[i] = src[i] + ((i + ofs) < 2048 ? src[i + ofs] : 0u);
            __syncthreads();
            unsigned* t = src; src = dst; dst = t;
        }
        for (int i = tid; i < 2048; i += 1024) {
            const unsigned s = src[i];
            const unsigned sn = (i < 2047) ? src[i + 1] : 0u;
            if (s >= need && sn < need) { sc[0] = (unsigned)i; sc[1] = sn; }
        }
        __syncthreads();
        const unsigned bb = sc[0];
        need -= sc[1];
        if (lvl == 0) b1 = bb;
        else if (lvl == 1) b2 = bb;
        else {
            const unsigned T = (b1 << 21) | (b2 << 10) | bb;
            const unsigned G = PRE - need;    // count strictly greater than T
            __syncthreads();
            for (int i = tid; i < 2048; i += 1024) s64[i] = 0ull;
            __syncthreads();
            // compaction with wave-aggregated counters
            for (int i = tid; i < 9216; i += 1024) {
                const uint4 kv = kp4[i];
#pragma unroll
                for (int c = 0; c < 4; c++) {
                    const unsigned k = (&kv.x)[c];
                    const unsigned ei = (unsigned)(i * 4 + c);
                    const bool pg_ = (k > T);
                    const bool pe_ = (k == T);
                    const unsigned long long mg = __ballot(pg_);
                    if (mg) {
                        const int ldr = __ffsll((long long)mg) - 1;
                        unsigned bg = 0;
                        if (lane == ldr) bg = atomicAdd(&cntG, (unsigned)__popcll(mg));
                        bg = (unsigned)__shfl((int)bg, ldr, 64);
                        if (pg_) {
                            const unsigned p = bg + (unsigned)__popcll(mg & ((1ull << lane) - 1ull));
                            s64[p] = ((unsigned long long)k << 32) | (unsigned)(~ei);
                        }
                    }
                    const unsigned long long me = __ballot(pe_);
                    if (me) {
                        const int ldr = __ffsll((long long)me) - 1;
                        unsigned be = 0;
                        if (lane == ldr) be = atomicAdd(&cntE, (unsigned)__popcll(me));
                        be = (unsigned)__shfl((int)be, ldr, 64);
                        if (pe_) {
                            const unsigned p = be + (unsigned)__popcll(me & ((1ull << lane) - 1ull));
                            if (G + p < 2048u)
                                s64[G + p] = ((unsigned long long)k << 32) | (unsigned)(~ei);
                        }
                    }
                }
            }
            __syncthreads();
            // bitonic sort desc; ties (equal key) -> ~idx desc -> idx asc
            for (unsigned ksz = 2; ksz <= 2048; ksz <<= 1) {
                for (unsigned jst = ksz >> 1; jst > 0; jst >>= 1) {
                    const unsigned i = (unsigned)tid;
                    const unsigned low = i & (jst - 1);
                    const unsigned l = ((i ^ low) << 1) | low;
                    const unsigned pr = l | jst;
                    const unsigned long long va = s64[l], vb = s64[pr];
                    const bool desc = (l & ksz) == 0;
                    if ((va < vb) == desc) { s64[l] = vb; s64[pr] = va; }
                    __syncthreads();
                }
            }
            // build SoA boxes + live bitmask
            const unsigned KEYNEG = ~__float_as_uint(-1e9f);
            for (int j = tid; j < 2048; j += 1024) {
                const unsigned long long v = s64[j];
                const unsigned key = (unsigned)(v >> 32);
                const unsigned idx = ~(unsigned)(v & 0xFFFFFFFFull);
                float4 box = {0.f, 0.f, 0.f, 0.f};
                if (key > KEYNEG) box = *(const float4*)&rois[((size_t)n * HWA + idx) * 4];
                sy1[j] = box.x; sx1[j] = box.y; sy2[j] = box.z; sx2[j] = box.w;
                const bool lb = (j < PRE) && (key > KEYNEG);
                const unsigned long long m = __ballot(lb);
                if (lane == 0) lwS[j >> 6] = m;
            }
            __syncthreads();

            // ---- greedy NMS: single wave, no barriers ----
            if (tid < 64) {
                float* outp = out + (size_t)n * (POST * 4);
                for (int it = 0; it < POST; it++) {
                    const unsigned long long wv_ = (lane < 32) ? lwS[lane] : 0ull;
                    unsigned cand = (wv_ != 0ull)
                        ? ((unsigned)lane * 64u + (unsigned)(__ffsll((long long)wv_) - 1))
                        : 0xFFFFFFFFu;
#pragma unroll
                    for (int off = 32; off; off >>= 1)
                        cand = umin2(cand, (unsigned)__shfl_xor((int)cand, off, 64));
                    const unsigned j = cand;

                    float4 ob = {0.f, 0.f, 0.f, 0.f};
                    if (j != 0xFFFFFFFFu) {
                        const float jy1 = sy1[j], jx1 = sx1[j], jy2 = sy2[j], jx2 = sx2[j];
                        const float a1 = (jy2 - jy1) * (jx2 - jx1);
                        const int cw = (int)(j >> 6);
                        for (int c = cw; c < 32; c++) {
                            const unsigned long long w = lwS[c];
                            if (w == 0ull) continue;          // uniform skip
                            const int bx_ = c * 64 + lane;
                            const bool live = (w >> lane) & 1ull;
                            const float ty = fmaxf(jy1, sy1[bx_]), tx = fmaxf(jx1, sx1[bx_]);
                            const float by = fminf(jy2, sy2[bx_]), bxx = fminf(jx2, sx2[bx_]);
                            const float ih = fmaxf(by - ty, 0.f), iw_ = fmaxf(bxx - tx, 0.f);
                            const float inter = ih * iw_;
                            const float a2 = (sy2[bx_] - sy1[bx_]) * (sx2[bx_] - sx1[bx_]);
                            const float iou = inter / ((a1 + a2) - inter);  // exact fp32 div
                            const unsigned long long supp = __ballot(live && (iou > 0.7f));
                            if (lane == 0) lwS[c] = w & ~supp;   // kills j too (iou=1)
                        }
                        asm volatile("s_waitcnt lgkmcnt(0)" ::: "memory");
                        ob = make_float4(jy1, jx1, jy2, jx2);
                    }
                    if (lane == 0) *(float4*)&outp[it * 4] = ob;
                }
            }
            return;
        }
        __syncthreads();
    }
}

// ---------------------------------------------------------------------------
extern "C" void kernel_launch(void* const* d_in, const int* in_sizes, int n_in,
                              void* d_out, int out_size, void* d_ws, size_t ws_size,
                              hipStream_t stream)
{
    // d_in: 0=images(unused) 1=features 2=w_conv 3=b_conv 4=w_score 5=b_score 6=w_loc 7=b_loc
    const float* feat  = (const float*)d_in[1];
    const float* wconv = (const float*)d_in[2];
    const float* bconv = (const float*)d_in[3];
    const float* wsc   = (const float*)d_in[4];
    const float* bsc   = (const float*)d_in[5];
    const float* wlc   = (const float*)d_in[6];
    const float* blc   = (const float*)d_in[7];
    float* out = (float*)d_out;

    char* ws = (char*)d_ws;
    float*    h    = (float*)(ws);                   // 33,554,432 B
    float*    wt3  = (float*)(ws + 33554432);        //  2,359,296 B
    float*    rois = (float*)(ws + 35913728);        //  4,718,592 B
    unsigned* keys = (unsigned*)(ws + 40632320);     //  1,179,648 B (total ~41.8 MB)

    prep_wt3       <<<dim3(768),  dim3(256),  0, stream>>>(wconv, wt3);
    conv3x3_relu_v5<<<dim3(2048), dim3(256),  0, stream>>>(feat, wt3, bconv, h);
    head_decode    <<<dim3(512),  dim3(256),  0, stream>>>(h, wsc, bsc, wlc, blc, keys, rois);
    topk_nms       <<<dim3(8),    dim3(1024), 0, stream>>>(keys, rois, out);
}

// Round 6
// 1402.107 us; speedup vs baseline: 1.8934x; 1.8934x over previous
//
#include <hip/hip_runtime.h>
#include <stdint.h>

#define NIMG 8
#define HFW  64
#define HWA  36864     // 64*64*9
#define PRE  2000
#define POST 300

#define AS1 __attribute__((address_space(1)))
#define AS3 __attribute__((address_space(3)))

__device__ __forceinline__ unsigned keyOf(float f) {
    unsigned u = __float_as_uint(f);
    return (u & 0x80000000u) ? ~u : (u | 0x80000000u);
}
__device__ __forceinline__ unsigned umin2(unsigned a, unsigned b){ return a < b ? a : b; }

// ---------------------------------------------------------------------------
// K0: w_conv [co][ci][3][3] -> wt3 [(ci*3+ky)*64 + co/4][ (co&3)*3 + kx ]
// ---------------------------------------------------------------------------
__global__ void prep_wt3(const float* __restrict__ w, float* __restrict__ wt3) {
    int t = blockIdx.x * 256 + threadIdx.x;      // t = (ci*3+ky)*256 + co
    if (t >= 256 * 3 * 256) return;
    int co = t & 255;
    int r  = t >> 8;            // ci*3+ky
    int ky = r % 3, ci = r / 3;
    const float* s = w + ((size_t)(co * 256 + ci)) * 9 + ky * 3;
    float* d = wt3 + ((size_t)((ci * 3 + ky) * 64 + (co >> 2))) * 12 + (co & 3) * 3;
    d[0] = s[0]; d[1] = s[1]; d[2] = s[2];
}

// ---------------------------------------------------------------------------
// K1 v5: 3x3 conv SAME + bias + relu.  fp32 VALU, scalar weights (SGPR),
// global_load_lds staging, XCD-pinned, 2048 blocks x 256 thr, 19.6KB LDS.
// ---------------------------------------------------------------------------
__global__ __launch_bounds__(256, 8) void conv3x3_relu_v5(const float* __restrict__ feat,
        const float* __restrict__ wt3, const float* __restrict__ bconv,
        float* __restrict__ h)
{
    __shared__ __align__(16) float sAll[2 * 2 * 18 * 68];   // 19,584 B

    const int tid  = threadIdx.x;
    const int lane = tid & 63;
    const int wv   = tid >> 6;          // wave 0..3
    const int b    = blockIdx.x;
    const int n    = b & 7;             // XCD-pinned image
    const int rem  = b >> 3;
    const int cog  = rem & 63;          // 0..63  (4 co each)
    const int y0   = (rem >> 6) << 4;   // 0,16,32,48
    const int pg   = tid & 15;
    const int px   = pg * 4;
    const int rr   = tid >> 4;          // 0..15 output row in strip

    const float* fb = feat + (size_t)n * 1048576;

    {
        const float4 z4 = {0.f, 0.f, 0.f, 0.f};
        for (int i = tid * 4; i < 4896; i += 1024) *(float4*)&sAll[i] = z4;
    }
    __syncthreads();

    float acc[4][4];
#pragma unroll
    for (int a = 0; a < 4; a++)
#pragma unroll
        for (int c = 0; c < 4; c++) acc[a][c] = 0.0f;

    const int sl_i = wv >> 1;
    const int sl_r = (wv & 1) * 9;
#define ISSUE_CK(CK, BUF) {                                                  \
        const float* _gb = fb + (size_t)((CK) * 2 + sl_i) * 4096 + lane;     \
        float* _lb = (BUF) + (sl_i * 18 + sl_r) * 68 + 1;                    \
        _Pragma("unroll")                                                    \
        for (int _q = 0; _q < 9; _q++) {                                     \
            const int _gy = y0 - 1 + sl_r + _q;                              \
            if (_gy >= 0 && _gy < 64)                                        \
                __builtin_amdgcn_global_load_lds(                            \
                    (const AS1 void*)(_gb + _gy * 64),                       \
                    (AS3 void*)(_lb + _q * 68), 4, 0, 0);                    \
        } }

    ISSUE_CK(0, sAll);
    asm volatile("s_waitcnt vmcnt(0)" ::: "memory");
    __syncthreads();

    for (int ck = 0; ck < 128; ck++) {
        const int ci0 = ck * 2;
        const float* bufc = sAll + (ck & 1) * 2448;
        float*       bufn = sAll + ((ck + 1) & 1) * 2448;

        if (ck < 127) ISSUE_CK(ck + 1, bufn);

        const float* rbase = bufc + rr * 68 + px;
#pragma unroll
        for (int i = 0; i < 2; i++) {
#pragma unroll
            for (int ky = 0; ky < 3; ky++) {
                const float* rowp = rbase + (i * 18 + ky) * 68;
                const float4 fA = *(const float4*)rowp;        // cols px-1..px+2
                const float2 fB = *(const float2*)(rowp + 4);  // cols px+3..px+4
                const float fc0 = fA.x, fc1 = fA.y, fc2 = fA.z, fc3 = fA.w;
                const float fc4 = fB.x, fc5 = fB.y;
                const float* wq = wt3 + (size_t)(((ci0 + i) * 3 + ky) * 64 + cog) * 12;
#pragma unroll
                for (int cc = 0; cc < 4; cc++) {
                    const float w0 = wq[cc * 3 + 0], w1 = wq[cc * 3 + 1], w2 = wq[cc * 3 + 2];
                    acc[cc][0] = fmaf(w0, fc0, acc[cc][0]);
                    acc[cc][0] = fmaf(w1, fc1, acc[cc][0]);
                    acc[cc][0] = fmaf(w2, fc2, acc[cc][0]);
                    acc[cc][1] = fmaf(w0, fc1, acc[cc][1]);
                    acc[cc][1] = fmaf(w1, fc2, acc[cc][1]);
                    acc[cc][1] = fmaf(w2, fc3, acc[cc][1]);
                    acc[cc][2] = fmaf(w0, fc2, acc[cc][2]);
                    acc[cc][2] = fmaf(w1, fc3, acc[cc][2]);
                    acc[cc][2] = fmaf(w2, fc4, acc[cc][2]);
                    acc[cc][3] = fmaf(w0, fc3, acc[cc][3]);
                    acc[cc][3] = fmaf(w1, fc4, acc[cc][3]);
                    acc[cc][3] = fmaf(w2, fc5, acc[cc][3]);
                }
            }
        }

        asm volatile("s_waitcnt vmcnt(0)" ::: "memory");
        __syncthreads();
    }
#undef ISSUE_CK

#pragma unroll
    for (int cc = 0; cc < 4; cc++) {
        const int co = cog * 4 + cc;
        const float bb = bconv[co];
        float4 o;
        o.x = fmaxf(acc[cc][0] + bb, 0.f);
        o.y = fmaxf(acc[cc][1] + bb, 0.f);
        o.z = fmaxf(acc[cc][2] + bb, 0.f);
        o.w = fmaxf(acc[cc][3] + bb, 0.f);
        *(float4*)(h + ((size_t)(n * 256 + co)) * 4096 + (y0 + rr) * 64 + px) = o;
    }
}

// ---------------------------------------------------------------------------
// K2: 1x1 heads (scores 9, locs 36) + box decode + clip + validity -> keys/rois
// ---------------------------------------------------------------------------
__global__ __launch_bounds__(256) void head_decode(const float* __restrict__ h,
        const float* __restrict__ wsc, const float* __restrict__ bsc,
        const float* __restrict__ wlc, const float* __restrict__ blc,
        unsigned* __restrict__ keys, float* __restrict__ rois)
{
    __shared__ float sH[128][64];
    __shared__ float sOut[64][49];

    const int tid = threadIdx.x;
    const int n   = blockIdx.x & 7;
    const int y   = blockIdx.x >> 3;
    const int px  = tid & 63;
    const int sl  = tid >> 6;             // == wave id
    const int o0  = sl * 12;

    const float* wp[12];
#pragma unroll
    for (int j = 0; j < 12; j++) {
        const int o = o0 + j;
        wp[j] = (o < 36) ? (wlc + (size_t)o * 256)
                         : ((o < 45) ? (wsc + (size_t)(o - 36) * 256) : wsc);
    }
    float r[12];
#pragma unroll
    for (int j = 0; j < 12; j++) r[j] = 0.0f;

    const float* hb = h + (size_t)n * 1048576 + y * 64;
    for (int half = 0; half < 2; half++) {
        for (int task = tid; task < 2048; task += 256) {
            const int c = task >> 4, x4 = (task & 15) << 2;
            *(float4*)&sH[c][x4] =
                *(const float4*)(hb + (size_t)(half * 128 + c) * 4096 + x4);
        }
        __syncthreads();
        for (int c4 = 0; c4 < 128; c4 += 4) {
            const float h0 = sH[c4][px], h1 = sH[c4 + 1][px];
            const float h2 = sH[c4 + 2][px], h3 = sH[c4 + 3][px];
#pragma unroll
            for (int j = 0; j < 12; j++) {
                float4 w = *(const float4*)(wp[j] + half * 128 + c4);
                r[j] = fmaf(h0, w.x, r[j]); r[j] = fmaf(h1, w.y, r[j]);
                r[j] = fmaf(h2, w.z, r[j]); r[j] = fmaf(h3, w.w, r[j]);
            }
        }
        __syncthreads();
    }
#pragma unroll
    for (int j = 0; j < 12; j++) {
        const int o = o0 + j;
        if (o < 45) {
            const float bias = (o < 36) ? blc[o] : bsc[o - 36];
            sOut[px][o] = r[j] + bias;
        }
    }
    __syncthreads();

    for (int a = sl; a < 9; a += 4) {
        const float s  = sOut[px][36 + a];
        const float dy = sOut[px][a * 4 + 0], dx = sOut[px][a * 4 + 1];
        const float dh = sOut[px][a * 4 + 2], dw = sOut[px][a * 4 + 3];
        const int si = a / 3, ri = a - si * 3;
        const float scale = (si == 0) ? 64.f : ((si == 1) ? 128.f : 256.f);
        const float rat   = (ri == 0) ? 0.5f : ((ri == 1) ? 1.f : 2.f);
        const float sq = __fsqrt_rn(rat);
        const float hs = __fmul_rn(scale, sq);
        const float ws = __fdiv_rn(scale, sq);
        const float cy = (y  + 0.5f) * 16.0f;   // exact
        const float cx = (px + 0.5f) * 16.0f;
        const float y1 = __fsub_rn(cy, __fmul_rn(hs, 0.5f));
        const float x1 = __fsub_rn(cx, __fmul_rn(ws, 0.5f));
        const float y2 = __fadd_rn(cy, __fmul_rn(hs, 0.5f));
        const float x2 = __fadd_rn(cx, __fmul_rn(ws, 0.5f));
        const float ah = __fsub_rn(y2, y1), aw = __fsub_rn(x2, x1);
        const float acy = __fadd_rn(y1, __fmul_rn(0.5f, ah));
        const float acx = __fadd_rn(x1, __fmul_rn(0.5f, aw));
        const float pcy = __fadd_rn(__fmul_rn(dy, ah), acy);
        const float pcx = __fadd_rn(__fmul_rn(dx, aw), acx);
        const float ph  = __fmul_rn(expf(dh), ah);
        const float pw  = __fmul_rn(expf(dw), aw);
        float by1 = __fsub_rn(pcy, __fmul_rn(0.5f, ph));
        float bx1 = __fsub_rn(pcx, __fmul_rn(0.5f, pw));
        float by2 = __fadd_rn(pcy, __fmul_rn(0.5f, ph));
        float bx2 = __fadd_rn(pcx, __fmul_rn(0.5f, pw));
        by1 = fminf(fmaxf(by1, 0.f), 1024.f); by2 = fminf(fmaxf(by2, 0.f), 1024.f);
        bx1 = fminf(fmaxf(bx1, 0.f), 1024.f); bx2 = fminf(fmaxf(bx2, 0.f), 1024.f);
        const float bh = __fsub_rn(by2, by1), bw = __fsub_rn(bx2, bx1);
        const bool valid = (bh >= 16.f) && (bw >= 16.f) && (s >= 0.f);
        const float sm = valid ? s : -1e9f;
        const int idx = (y * 64 + px) * 9 + a;
        keys[(size_t)n * HWA + idx] = keyOf(sm);
        float4 bxv = {by1, bx1, by2, bx2};
        *(float4*)&rois[((size_t)n * HWA + idx) * 4] = bxv;
    }
}

// ---------------------------------------------------------------------------
// K3: exact top-2000 sorted (key desc, idx asc): 3-level histogram select
//     (wave-aggregated atomics) + compaction + 2048 bitonic sort -> bk/tkey.
// ---------------------------------------------------------------------------
__global__ __launch_bounds__(1024) void topk_sort(const unsigned* __restrict__ keys,
        const float* __restrict__ rois, float* __restrict__ bk,
        unsigned* __restrict__ tkey)
{
    __shared__ unsigned long long s64[2048];     // 16 KB; aliased as 2x u32[2048]
    __shared__ unsigned sc[2];
    __shared__ unsigned cntG, cntE;
    unsigned* histA = (unsigned*)&s64[0];
    unsigned* histB = histA + 2048;

    const int tid  = threadIdx.x;
    const int lane = tid & 63;
    const int n    = blockIdx.x;
    const unsigned* kp = keys + (size_t)n * HWA;
    const uint4* kp4 = (const uint4*)kp;
    const unsigned KNEG = keyOf(-1e9f);

    unsigned need = PRE;
    unsigned b1 = 0, b2 = 0;

    for (int lvl = 0; lvl < 3; lvl++) {
        for (int i = tid; i < 2048; i += 1024) histA[i] = 0u;
        if (tid == 0) { cntG = 0u; cntE = 0u; }
        __syncthreads();
        for (int i = tid; i < 9216; i += 1024) {
            const uint4 kv = kp4[i];
#pragma unroll
            for (int c = 0; c < 4; c++) {
                const unsigned k = (&kv.x)[c];
                if (lvl == 0) {
                    // wave-aggregate the massive -1e9 class
                    const bool ineg = (k == KNEG);
                    const unsigned long long mn = __ballot(ineg);
                    if (ineg) {
                        if (lane == __ffsll((long long)mn) - 1)
                            atomicAdd(&histA[KNEG >> 21], (unsigned)__popcll(mn));
                    } else {
                        atomicAdd(&histA[k >> 21], 1u);
                    }
                } else if (lvl == 1) {
                    if ((k >> 21) == b1) atomicAdd(&histA[(k >> 10) & 2047u], 1u);
                } else {
                    if ((k >> 10) == ((b1 << 11) | b2)) atomicAdd(&histA[k & 1023u], 1u);
                }
            }
        }
        __syncthreads();
        unsigned *src = histA, *dst = histB;
        for (int ofs = 1; ofs < 2048; ofs <<= 1) {
            for (int i = tid; i < 2048; i += 1024)
                dst[i] = src[i] + ((i + ofs) < 2048 ? src[i + ofs] : 0u);
            __syncthreads();
            unsigned* t = src; src = dst; dst = t;
        }
        for (int i = tid; i < 2048; i += 1024) {
            const unsigned s = src[i];
            const unsigned sn = (i < 2047) ? src[i + 1] : 0u;
            if (s >= need && sn < need) { sc[0] = (unsigned)i; sc[1] = sn; }
        }
        __syncthreads();
        const unsigned bb = sc[0];
        need -= sc[1];
        if (lvl == 0) b1 = bb;
        else if (lvl == 1) b2 = bb;
        else {
            const unsigned T = (b1 << 21) | (b2 << 10) | bb;
            const unsigned G = PRE - need;    // count strictly greater than T
            __syncthreads();
            for (int i = tid; i < 2048; i += 1024) s64[i] = 0ull;
            __syncthreads();
            // compaction with wave-aggregated counters
            for (int i = tid; i < 9216; i += 1024) {
                const uint4 kv = kp4[i];
#pragma unroll
                for (int c = 0; c < 4; c++) {
                    const unsigned k = (&kv.x)[c];
                    const unsigned ei = (unsigned)(i * 4 + c);
                    const bool pg_ = (k > T);
                    const bool pe_ = (k == T);
                    const unsigned long long mg = __ballot(pg_);
                    if (mg) {
                        const int ldr = __ffsll((long long)mg) - 1;
                        unsigned bg = 0;
                        if (lane == ldr) bg = atomicAdd(&cntG, (unsigned)__popcll(mg));
                        bg = (unsigned)__shfl((int)bg, ldr, 64);
                        if (pg_) {
                            const unsigned p = bg + (unsigned)__popcll(mg & ((1ull << lane) - 1ull));
                            s64[p] = ((unsigned long long)k << 32) | (unsigned)(~ei);
                        }
                    }
                    const unsigned long long me = __ballot(pe_);
                    if (me) {
                        const int ldr = __ffsll((long long)me) - 1;
                        unsigned be = 0;
                        if (lane == ldr) be = atomicAdd(&cntE, (unsigned)__popcll(me));
                        be = (unsigned)__shfl((int)be, ldr, 64);
                        if (pe_) {
                            const unsigned p = be + (unsigned)__popcll(me & ((1ull << lane) - 1ull));
                            if (G + p < 2048u)
                                s64[G + p] = ((unsigned long long)k << 32) | (unsigned)(~ei);
                        }
                    }
                }
            }
            __syncthreads();
            // bitonic sort desc; ties (equal key) -> ~idx desc -> idx asc
            for (unsigned ksz = 2; ksz <= 2048; ksz <<= 1) {
                for (unsigned jst = ksz >> 1; jst > 0; jst >>= 1) {
                    const unsigned i = (unsigned)tid;
                    const unsigned low = i & (jst - 1);
                    const unsigned l = ((i ^ low) << 1) | low;
                    const unsigned pr = l | jst;
                    const unsigned long long va = s64[l], vb = s64[pr];
                    const bool desc = (l & ksz) == 0;
                    if ((va < vb) == desc) { s64[l] = vb; s64[pr] = va; }
                    __syncthreads();
                }
            }
            const unsigned KEYNEG = ~__float_as_uint(-1e9f);
            for (int j = tid; j < 2048; j += 1024) {
                const unsigned long long v = s64[j];
                const unsigned key = (unsigned)(v >> 32);
                const unsigned idx = ~(unsigned)(v & 0xFFFFFFFFull);
                float4 box = {0.f, 0.f, 0.f, 0.f};
                if (key > KEYNEG) box = *(const float4*)&rois[((size_t)n * HWA + idx) * 4];
                *(float4*)&bk[((size_t)n * 2048 + j) * 4] = box;
                tkey[(size_t)n * 2048 + j] = (j < PRE) ? key : 0u;
            }
            return;
        }
        __syncthreads();
    }
}

// ---------------------------------------------------------------------------
// K4: greedy NMS, register-resident boxes.  256 thr/image, thread t owns
// boxes k = q*256+t (q=0..7) entirely in VGPRs; live mask is a register.
// Exactly 2 barriers per iteration; IoU path touches no LDS.
// ---------------------------------------------------------------------------
__global__ __launch_bounds__(256) void nms_reg(const float* __restrict__ bk,
        const unsigned* __restrict__ tkey, float* __restrict__ out)
{
    __shared__ float jb[4];           // selected box broadcast
    __shared__ unsigned sRed[4];

    const int tid  = threadIdx.x;
    const int lane = tid & 63;
    const int n    = blockIdx.x;
    const unsigned KEYNEG = ~__float_as_uint(-1e9f);
    const unsigned INF = 0xFFFFFFFFu;

    float y1[8], x1[8], y2[8], x2[8], a2[8];
    unsigned live = 0;
#pragma unroll
    for (int q = 0; q < 8; q++) {
        const int k = q * 256 + tid;
        float4 b = *(const float4*)&bk[((size_t)n * 2048 + k) * 4];
        y1[q] = b.x; x1[q] = b.y; y2[q] = b.z; x2[q] = b.w;
        a2[q] = (b.z - b.x) * (b.w - b.y);
        if (k < PRE && tkey[(size_t)n * 2048 + k] > KEYNEG) live |= (1u << q);
    }
    if (n == 0 && tid == 0) out[9600] = 0.0f;   // rpn_loss
    float* outp = out + (size_t)n * (POST * 4);

    for (int it = 0; it < POST; it++) {
        // ---- first live k = min over threads of ((ffs(live)-1)*256 + t)
        unsigned cand = live ? ((((unsigned)__ffs(live) - 1u) << 8) | (unsigned)tid) : INF;
#pragma unroll
        for (int off = 32; off; off >>= 1)
            cand = umin2(cand, (unsigned)__shfl_xor((int)cand, off, 64));
        if (lane == 0) sRed[tid >> 6] = cand;
        __syncthreads();
        const unsigned j = umin2(umin2(sRed[0], sRed[1]), umin2(sRed[2], sRed[3]));

        // ---- owner publishes box j
        if (j != INF && tid == (int)(j & 255u)) {
            const int q = (int)(j >> 8);
            jb[0] = y1[q]; jb[1] = x1[q]; jb[2] = y2[q]; jb[3] = x2[q];
        }
        __syncthreads();

        // ---- IoU from registers; clear live bits
        if (j != INF) {
            const float jy1 = jb[0], jx1 = jb[1], jy2 = jb[2], jx2 = jb[3];
            const float a1 = (jy2 - jy1) * (jx2 - jx1);
            unsigned lv = live;
            while (lv) {
                const int q = __ffs(lv) - 1;
                lv &= lv - 1;
                const float ty = fmaxf(jy1, y1[q]), tx = fmaxf(jx1, x1[q]);
                const float by = fminf(jy2, y2[q]), bx = fminf(jx2, x2[q]);
                const float ih = fmaxf(by - ty, 0.f), iw = fmaxf(bx - tx, 0.f);
                const float inter = ih * iw;
                const float iou = inter / ((a1 + a2[q]) - inter);  // exact fp32 div
                if (iou > 0.7f) live &= ~(1u << q);   // kills j itself (iou=1)
            }
            if (tid == 0) {
                float4 ob = {jy1, jx1, jy2, jx2};
                *(float4*)&outp[it * 4] = ob;
            }
        } else if (tid == 0) {
            const float4 zb = {0.f, 0.f, 0.f, 0.f};
            *(float4*)&outp[it * 4] = zb;
        }
        // (the next iteration's sRed/jb writes happen after every thread has
        //  passed this point; barrier at top of next iteration protects reuse)
        __syncthreads();
    }
}

// ---------------------------------------------------------------------------
extern "C" void kernel_launch(void* const* d_in, const int* in_sizes, int n_in,
                              void* d_out, int out_size, void* d_ws, size_t ws_size,
                              hipStream_t stream)
{
    // d_in: 0=images(unused) 1=features 2=w_conv 3=b_conv 4=w_score 5=b_score 6=w_loc 7=b_loc
    const float* feat  = (const float*)d_in[1];
    const float* wconv = (const float*)d_in[2];
    const float* bconv = (const float*)d_in[3];
    const float* wsc   = (const float*)d_in[4];
    const float* bsc   = (const float*)d_in[5];
    const float* wlc   = (const float*)d_in[6];
    const float* blc   = (const float*)d_in[7];
    float* out = (float*)d_out;

    char* ws = (char*)d_ws;
    float*    h    = (float*)(ws);                   // 33,554,432 B
    float*    wt3  = (float*)(ws + 33554432);        //  2,359,296 B
    float*    rois = (float*)(ws + 35913728);        //  4,718,592 B
    unsigned* keys = (unsigned*)(ws + 40632320);     //  1,179,648 B
    float*    bk   = (float*)(ws + 41811968);        //    262,144 B
    unsigned* tkey = (unsigned*)(ws + 42074112);     //     65,536 B  (total ~42.1 MB)

    prep_wt3       <<<dim3(768),  dim3(256),  0, stream>>>(wconv, wt3);
    conv3x3_relu_v5<<<dim3(2048), dim3(256),  0, stream>>>(feat, wt3, bconv, h);
    head_decode    <<<dim3(512),  dim3(256),  0, stream>>>(h, wsc, bsc, wlc, blc, keys, rois);
    topk_sort      <<<dim3(8),    dim3(1024), 0, stream>>>(keys, rois, bk, tkey);
    nms_reg        <<<dim3(8),    dim3(256),  0, stream>>>(bk, tkey, out);
}

// Round 7
// 1035.178 us; speedup vs baseline: 2.5645x; 1.3545x over previous
//
#include <hip/hip_runtime.h>
#include <stdint.h>

#define NIMG 8
#define HFW  64
#define HWA  36864     // 64*64*9
#define PRE  2000
#define POST 300

#define AS1 __attribute__((address_space(1)))
#define AS3 __attribute__((address_space(3)))

__device__ __forceinline__ unsigned keyOf(float f) {
    unsigned u = __float_as_uint(f);
    return (u & 0x80000000u) ? ~u : (u | 0x80000000u);
}
__device__ __forceinline__ unsigned umin2(unsigned a, unsigned b){ return a < b ? a : b; }

// ---------------------------------------------------------------------------
// K0: w_conv -> wt3 [(ci*3+ky)*64 + co/4][(co&3)*3 + kx]; also zero ghist.
// ---------------------------------------------------------------------------
__global__ void prep_wt3(const float* __restrict__ w, float* __restrict__ wt3,
                         unsigned* __restrict__ ghist) {
    int t = blockIdx.x * 256 + threadIdx.x;      // t = (ci*3+ky)*256 + co
    if (t < 16384) ghist[t] = 0u;                // 8 images x 2048 bins
    if (t >= 256 * 3 * 256) return;
    int co = t & 255;
    int r  = t >> 8;            // ci*3+ky
    int ky = r % 3, ci = r / 3;
    const float* s = w + ((size_t)(co * 256 + ci)) * 9 + ky * 3;
    float* d = wt3 + ((size_t)((ci * 3 + ky) * 64 + (co >> 2))) * 12 + (co & 3) * 3;
    d[0] = s[0]; d[1] = s[1]; d[2] = s[2];
}

// ---------------------------------------------------------------------------
// K1 v5 (unchanged): 3x3 conv SAME + bias + relu.
// ---------------------------------------------------------------------------
__global__ __launch_bounds__(256, 8) void conv3x3_relu_v5(const float* __restrict__ feat,
        const float* __restrict__ wt3, const float* __restrict__ bconv,
        float* __restrict__ h)
{
    __shared__ __align__(16) float sAll[2 * 2 * 18 * 68];   // 19,584 B

    const int tid  = threadIdx.x;
    const int lane = tid & 63;
    const int wv   = tid >> 6;
    const int b    = blockIdx.x;
    const int n    = b & 7;             // XCD-pinned image
    const int rem  = b >> 3;
    const int cog  = rem & 63;          // 0..63  (4 co each)
    const int y0   = (rem >> 6) << 4;   // 0,16,32,48
    const int pg   = tid & 15;
    const int px   = pg * 4;
    const int rr   = tid >> 4;

    const float* fb = feat + (size_t)n * 1048576;

    {
        const float4 z4 = {0.f, 0.f, 0.f, 0.f};
        for (int i = tid * 4; i < 4896; i += 1024) *(float4*)&sAll[i] = z4;
    }
    __syncthreads();

    float acc[4][4];
#pragma unroll
    for (int a = 0; a < 4; a++)
#pragma unroll
        for (int c = 0; c < 4; c++) acc[a][c] = 0.0f;

    const int sl_i = wv >> 1;
    const int sl_r = (wv & 1) * 9;
#define ISSUE_CK(CK, BUF) {                                                  \
        const float* _gb = fb + (size_t)((CK) * 2 + sl_i) * 4096 + lane;     \
        float* _lb = (BUF) + (sl_i * 18 + sl_r) * 68 + 1;                    \
        _Pragma("unroll")                                                    \
        for (int _q = 0; _q < 9; _q++) {                                     \
            const int _gy = y0 - 1 + sl_r + _q;                              \
            if (_gy >= 0 && _gy < 64)                                        \
                __builtin_amdgcn_global_load_lds(                            \
                    (const AS1 void*)(_gb + _gy * 64),                       \
                    (AS3 void*)(_lb + _q * 68), 4, 0, 0);                    \
        } }

    ISSUE_CK(0, sAll);
    asm volatile("s_waitcnt vmcnt(0)" ::: "memory");
    __syncthreads();

    for (int ck = 0; ck < 128; ck++) {
        const int ci0 = ck * 2;
        const float* bufc = sAll + (ck & 1) * 2448;
        float*       bufn = sAll + ((ck + 1) & 1) * 2448;

        if (ck < 127) ISSUE_CK(ck + 1, bufn);

        const float* rbase = bufc + rr * 68 + px;
#pragma unroll
        for (int i = 0; i < 2; i++) {
#pragma unroll
            for (int ky = 0; ky < 3; ky++) {
                const float* rowp = rbase + (i * 18 + ky) * 68;
                const float4 fA = *(const float4*)rowp;
                const float2 fB = *(const float2*)(rowp + 4);
                const float fc0 = fA.x, fc1 = fA.y, fc2 = fA.z, fc3 = fA.w;
                const float fc4 = fB.x, fc5 = fB.y;
                const float* wq = wt3 + (size_t)(((ci0 + i) * 3 + ky) * 64 + cog) * 12;
#pragma unroll
                for (int cc = 0; cc < 4; cc++) {
                    const float w0 = wq[cc * 3 + 0], w1 = wq[cc * 3 + 1], w2 = wq[cc * 3 + 2];
                    acc[cc][0] = fmaf(w0, fc0, acc[cc][0]);
                    acc[cc][0] = fmaf(w1, fc1, acc[cc][0]);
                    acc[cc][0] = fmaf(w2, fc2, acc[cc][0]);
                    acc[cc][1] = fmaf(w0, fc1, acc[cc][1]);
                    acc[cc][1] = fmaf(w1, fc2, acc[cc][1]);
                    acc[cc][1] = fmaf(w2, fc3, acc[cc][1]);
                    acc[cc][2] = fmaf(w0, fc2, acc[cc][2]);
                    acc[cc][2] = fmaf(w1, fc3, acc[cc][2]);
                    acc[cc][2] = fmaf(w2, fc4, acc[cc][2]);
                    acc[cc][3] = fmaf(w0, fc3, acc[cc][3]);
                    acc[cc][3] = fmaf(w1, fc4, acc[cc][3]);
                    acc[cc][3] = fmaf(w2, fc5, acc[cc][3]);
                }
            }
        }

        asm volatile("s_waitcnt vmcnt(0)" ::: "memory");
        __syncthreads();
    }
#undef ISSUE_CK

#pragma unroll
    for (int cc = 0; cc < 4; cc++) {
        const int co = cog * 4 + cc;
        const float bb = bconv[co];
        float4 o;
        o.x = fmaxf(acc[cc][0] + bb, 0.f);
        o.y = fmaxf(acc[cc][1] + bb, 0.f);
        o.z = fmaxf(acc[cc][2] + bb, 0.f);
        o.w = fmaxf(acc[cc][3] + bb, 0.f);
        *(float4*)(h + ((size_t)(n * 256 + co)) * 4096 + (y0 + rr) * 64 + px) = o;
    }
}

// ---------------------------------------------------------------------------
// K2 v2: 1x1 heads + decode.  Weights staged in LDS (46KB, broadcast reads);
// h in 4x 64-channel chunks (16KB, aliased by sOut at the end).
// Also builds the per-image 2048-bin key histogram (wave-aggregated atomics).
// ---------------------------------------------------------------------------
__global__ __launch_bounds__(256) void head_decode(const float* __restrict__ h,
        const float* __restrict__ wsc, const float* __restrict__ bsc,
        const float* __restrict__ wlc, const float* __restrict__ blc,
        unsigned* __restrict__ keys, float* __restrict__ rois,
        unsigned* __restrict__ ghist)
{
    __shared__ __align__(16) float sW[45 * 256];     // 46,080 B
    __shared__ __align__(16) float sHb[64 * 64];     // 16,384 B (reused as sOut)

    const int tid  = threadIdx.x;
    const int lane = tid & 63;
    const int n    = blockIdx.x & 7;
    const int y    = blockIdx.x >> 3;
    const int px   = tid & 63;
    const int sl   = tid >> 6;            // wave id
    const int o0   = sl * 12;

    // stage weights once (2880 float4)
    for (int t = tid; t < 2880; t += 256) {
        const int o  = t >> 6;                 // 0..44
        const int c4 = (t & 63) << 2;
        const float* src = (o < 36) ? (wlc + (size_t)o * 256 + c4)
                                    : (wsc + (size_t)(o - 36) * 256 + c4);
        *(float4*)&sW[o * 256 + c4] = *(const float4*)src;
    }

    float r[12];
#pragma unroll
    for (int j = 0; j < 12; j++) r[j] = 0.0f;

    const float* hb = h + (size_t)n * 1048576 + y * 64;
    for (int ch = 0; ch < 4; ch++) {
        __syncthreads();                       // sHb rewrite + (ch==0) weights ready
        for (int t = tid; t < 1024; t += 256) {
            const int c = t >> 4, q = (t & 15) << 2;
            *(float4*)&sHb[c * 64 + q] =
                *(const float4*)(hb + (size_t)(ch * 64 + c) * 4096 + q);
        }
        __syncthreads();
        for (int c4 = 0; c4 < 64; c4 += 4) {
            const float h0 = sHb[(c4 + 0) * 64 + px];
            const float h1 = sHb[(c4 + 1) * 64 + px];
            const float h2 = sHb[(c4 + 2) * 64 + px];
            const float h3 = sHb[(c4 + 3) * 64 + px];
#pragma unroll
            for (int j = 0; j < 12; j++) {
                const int o  = o0 + j;
                const int ov = (o < 45) ? o : 44;         // clamp (r[j] discarded)
                const float4 w = *(const float4*)&sW[ov * 256 + ch * 64 + c4];
                r[j] = fmaf(h0, w.x, r[j]); r[j] = fmaf(h1, w.y, r[j]);
                r[j] = fmaf(h2, w.z, r[j]); r[j] = fmaf(h3, w.w, r[j]);
            }
        }
    }
    __syncthreads();                           // all sHb reads done -> alias as sOut
    float* sOut = sHb;                         // [px*49 + o], 3136 <= 4096
#pragma unroll
    for (int j = 0; j < 12; j++) {
        const int o = o0 + j;
        if (o < 45) {
            const float bias = (o < 36) ? blc[o] : bsc[o - 36];
            sOut[px * 49 + o] = r[j] + bias;
        }
    }
    __syncthreads();

    // decode (reference fp32 op order; no contraction)
    for (int a = sl; a < 9; a += 4) {
        const float s  = sOut[px * 49 + 36 + a];
        const float dy = sOut[px * 49 + a * 4 + 0], dx = sOut[px * 49 + a * 4 + 1];
        const float dh = sOut[px * 49 + a * 4 + 2], dw = sOut[px * 49 + a * 4 + 3];
        const int si = a / 3, ri = a - si * 3;
        const float scale = (si == 0) ? 64.f : ((si == 1) ? 128.f : 256.f);
        const float rat   = (ri == 0) ? 0.5f : ((ri == 1) ? 1.f : 2.f);
        const float sq = __fsqrt_rn(rat);
        const float hs = __fmul_rn(scale, sq);
        const float ws = __fdiv_rn(scale, sq);
        const float cy = (y  + 0.5f) * 16.0f;
        const float cx = (px + 0.5f) * 16.0f;
        const float y1 = __fsub_rn(cy, __fmul_rn(hs, 0.5f));
        const float x1 = __fsub_rn(cx, __fmul_rn(ws, 0.5f));
        const float y2 = __fadd_rn(cy, __fmul_rn(hs, 0.5f));
        const float x2 = __fadd_rn(cx, __fmul_rn(ws, 0.5f));
        const float ah = __fsub_rn(y2, y1), aw = __fsub_rn(x2, x1);
        const float acy = __fadd_rn(y1, __fmul_rn(0.5f, ah));
        const float acx = __fadd_rn(x1, __fmul_rn(0.5f, aw));
        const float pcy = __fadd_rn(__fmul_rn(dy, ah), acy);
        const float pcx = __fadd_rn(__fmul_rn(dx, aw), acx);
        const float ph  = __fmul_rn(expf(dh), ah);
        const float pw  = __fmul_rn(expf(dw), aw);
        float by1 = __fsub_rn(pcy, __fmul_rn(0.5f, ph));
        float bx1 = __fsub_rn(pcx, __fmul_rn(0.5f, pw));
        float by2 = __fadd_rn(pcy, __fmul_rn(0.5f, ph));
        float bx2 = __fadd_rn(pcx, __fmul_rn(0.5f, pw));
        by1 = fminf(fmaxf(by1, 0.f), 1024.f); by2 = fminf(fmaxf(by2, 0.f), 1024.f);
        bx1 = fminf(fmaxf(bx1, 0.f), 1024.f); bx2 = fminf(fmaxf(bx2, 0.f), 1024.f);
        const float bh = __fsub_rn(by2, by1), bw = __fsub_rn(bx2, bx1);
        const bool valid = (bh >= 16.f) && (bw >= 16.f) && (s >= 0.f);
        const float sm = valid ? s : -1e9f;
        const unsigned key = keyOf(sm);
        const int idx = (y * 64 + px) * 9 + a;
        keys[(size_t)n * HWA + idx] = key;
        float4 bxv = {by1, bx1, by2, bx2};
        *(float4*)&rois[((size_t)n * HWA + idx) * 4] = bxv;

        // ---- lvl0 histogram: wave-aggregate by bucket, then global atomicAdd
        const unsigned bucket = key >> 21;
        unsigned long long todo = __ballot(true);
        while (todo) {
            const int ldr = __ffsll((long long)todo) - 1;
            const unsigned lb = (unsigned)__shfl((int)bucket, ldr, 64);
            const unsigned long long m = __ballot(bucket == lb);
            if (lane == ldr)
                atomicAdd(&ghist[n * 2048 + lb], (unsigned)__popcll(m));
            todo &= ~m;
        }
    }
}

// ---------------------------------------------------------------------------
// K3: exact top-2000 sorted.  lvl0 comes precomputed from ghist; lvl1/lvl2
// scans + compaction + 2048 bitonic sort.  1 block (1024 thr) per image.
// ---------------------------------------------------------------------------
__global__ __launch_bounds__(1024) void topk_sort(const unsigned* __restrict__ keys,
        const float* __restrict__ rois, const unsigned* __restrict__ ghist,
        float* __restrict__ bk, unsigned* __restrict__ tkey)
{
    __shared__ unsigned long long s64[2048];     // 16 KB; aliased as 2x u32[2048]
    __shared__ unsigned sc[2];
    __shared__ unsigned cntG, cntE;
    unsigned* histA = (unsigned*)&s64[0];
    unsigned* histB = histA + 2048;

    const int tid  = threadIdx.x;
    const int lane = tid & 63;
    const int n    = blockIdx.x;
    const uint4* kp4 = (const uint4*)(keys + (size_t)n * HWA);

    unsigned need = PRE;
    unsigned b1 = 0, b2 = 0, b3 = 0;

#define SUFFIX_PICK(BVAR) {                                                  \
        unsigned *src = histA, *dst = histB;                                 \
        for (int ofs = 1; ofs < 2048; ofs <<= 1) {                           \
            for (int i = tid; i < 2048; i += 1024)                           \
                dst[i] = src[i] + ((i + ofs) < 2048 ? src[i + ofs] : 0u);    \
            __syncthreads();                                                 \
            unsigned* t_ = src; src = dst; dst = t_;                         \
        }                                                                    \
        for (int i = tid; i < 2048; i += 1024) {                             \
            const unsigned s_ = src[i];                                      \
            const unsigned sn_ = (i < 2047) ? src[i + 1] : 0u;               \
            if (s_ >= need && sn_ < need) { sc[0] = (unsigned)i; sc[1] = sn_; } \
        }                                                                    \
        __syncthreads();                                                     \
        BVAR = sc[0];                                                        \
        need -= sc[1];                                                       \
    }

    // ---- phase A: lvl0 from precomputed ghist
    for (int i = tid; i < 2048; i += 1024) histA[i] = ghist[n * 2048 + i];
    if (tid == 0) { cntG = 0u; cntE = 0u; }
    __syncthreads();
    SUFFIX_PICK(b1);

    // ---- phase B: lvl1
    __syncthreads();
    for (int i = tid; i < 2048; i += 1024) histA[i] = 0u;
    __syncthreads();
    for (int i = tid; i < 9216; i += 1024) {
        const uint4 kv = kp4[i];
#pragma unroll
        for (int c = 0; c < 4; c++) {
            const unsigned k = (&kv.x)[c];
            if ((k >> 21) == b1) atomicAdd(&histA[(k >> 10) & 2047u], 1u);
        }
    }
    __syncthreads();
    SUFFIX_PICK(b2);

    // ---- phase C: lvl2
    __syncthreads();
    for (int i = tid; i < 2048; i += 1024) histA[i] = 0u;
    __syncthreads();
    for (int i = tid; i < 9216; i += 1024) {
        const uint4 kv = kp4[i];
#pragma unroll
        for (int c = 0; c < 4; c++) {
            const unsigned k = (&kv.x)[c];
            if ((k >> 10) == ((b1 << 11) | b2)) atomicAdd(&histA[k & 1023u], 1u);
        }
    }
    __syncthreads();
    SUFFIX_PICK(b3);
#undef SUFFIX_PICK

    const unsigned T = (b1 << 21) | (b2 << 10) | b3;
    const unsigned G = PRE - need;    // count strictly greater than T

    // ---- phase D: compaction + bitonic sort + output
    __syncthreads();
    for (int i = tid; i < 2048; i += 1024) s64[i] = 0ull;
    __syncthreads();
    for (int i = tid; i < 9216; i += 1024) {
        const uint4 kv = kp4[i];
#pragma unroll
        for (int c = 0; c < 4; c++) {
            const unsigned k = (&kv.x)[c];
            const unsigned ei = (unsigned)(i * 4 + c);
            const bool pg_ = (k > T);
            const bool pe_ = (k == T);
            const unsigned long long mg = __ballot(pg_);
            if (mg) {
                const int ldr = __ffsll((long long)mg) - 1;
                unsigned bg = 0;
                if (lane == ldr) bg = atomicAdd(&cntG, (unsigned)__popcll(mg));
                bg = (unsigned)__shfl((int)bg, ldr, 64);
                if (pg_) {
                    const unsigned p = bg + (unsigned)__popcll(mg & ((1ull << lane) - 1ull));
                    s64[p] = ((unsigned long long)k << 32) | (unsigned)(~ei);
                }
            }
            const unsigned long long me = __ballot(pe_);
            if (me) {
                const int ldr = __ffsll((long long)me) - 1;
                unsigned be = 0;
                if (lane == ldr) be = atomicAdd(&cntE, (unsigned)__popcll(me));
                be = (unsigned)__shfl((int)be, ldr, 64);
                if (pe_) {
                    const unsigned p = be + (unsigned)__popcll(me & ((1ull << lane) - 1ull));
                    if (G + p < 2048u)
                        s64[G + p] = ((unsigned long long)k << 32) | (unsigned)(~ei);
                }
            }
        }
    }
    __syncthreads();
    for (unsigned ksz = 2; ksz <= 2048; ksz <<= 1) {
        for (unsigned jst = ksz >> 1; jst > 0; jst >>= 1) {
            const unsigned i = (unsigned)tid;
            const unsigned low = i & (jst - 1);
            const unsigned l = ((i ^ low) << 1) | low;
            const unsigned pr = l | jst;
            const unsigned long long va = s64[l], vb = s64[pr];
            const bool desc = (l & ksz) == 0;
            if ((va < vb) == desc) { s64[l] = vb; s64[pr] = va; }
            __syncthreads();
        }
    }
    const unsigned KEYNEG = ~__float_as_uint(-1e9f);
    for (int j = tid; j < 2048; j += 1024) {
        const unsigned long long v = s64[j];
        const unsigned key = (unsigned)(v >> 32);
        const unsigned idx = ~(unsigned)(v & 0xFFFFFFFFull);
        float4 box = {0.f, 0.f, 0.f, 0.f};
        if (key > KEYNEG) box = *(const float4*)&rois[((size_t)n * HWA + idx) * 4];
        *(float4*)&bk[((size_t)n * 2048 + j) * 4] = box;
        tkey[(size_t)n * 2048 + j] = (j < PRE) ? key : 0u;
    }
}

// ---------------------------------------------------------------------------
// K4 v2: greedy NMS.  Boxes in registers with STATIC indexing only (rule #20);
// box j fetched via uniform LDS broadcast; 1 barrier/iter (parity-buffered).
// ---------------------------------------------------------------------------
__global__ __launch_bounds__(256) void nms_reg(const float* __restrict__ bk,
        const unsigned* __restrict__ tkey, float* __restrict__ out)
{
    __shared__ float sy1[2048], sx1[2048], sy2[2048], sx2[2048];
    __shared__ unsigned sRedP[2][4];

    const int tid  = threadIdx.x;
    const int lane = tid & 63;
    const int n    = blockIdx.x;
    const unsigned KEYNEG = ~__float_as_uint(-1e9f);
    const unsigned INF = 0xFFFFFFFFu;

    float y1[8], x1[8], y2[8], x2[8], a2[8];
    unsigned live = 0;
#pragma unroll
    for (int q = 0; q < 8; q++) {
        const int k = q * 256 + tid;
        float4 b = *(const float4*)&bk[((size_t)n * 2048 + k) * 4];
        y1[q] = b.x; x1[q] = b.y; y2[q] = b.z; x2[q] = b.w;
        a2[q] = (b.z - b.x) * (b.w - b.y);
        sy1[k] = b.x; sx1[k] = b.y; sy2[k] = b.z; sx2[k] = b.w;
        if (k < PRE && tkey[(size_t)n * 2048 + k] > KEYNEG) live |= (1u << q);
    }
    if (n == 0 && tid == 0) out[9600] = 0.0f;   // rpn_loss
    float* outp = out + (size_t)n * (POST * 4);
    __syncthreads();

    for (int it = 0; it < POST; it++) {
        // first live k  (k = q*256+tid; order-preserving encode (q<<8)|tid)
        unsigned cand = live ? ((((unsigned)__ffs(live) - 1u) << 8) | (unsigned)tid) : INF;
#pragma unroll
        for (int off = 32; off; off >>= 1)
            cand = umin2(cand, (unsigned)__shfl_xor((int)cand, off, 64));
        if (lane == 0) sRedP[it & 1][tid >> 6] = cand;
        __syncthreads();
        const unsigned* sr = sRedP[it & 1];
        const unsigned jj = umin2(umin2(sr[0], sr[1]), umin2(sr[2], sr[3]));

        if (jj != INF) {
            const unsigned j = ((jj >> 8) << 8) * 0 + ((jj & 255u) + ((jj >> 8) << 8));
            // decode back to box index: k = q*256 + t
            const unsigned kj = ((jj >> 8) * 256u) + (jj & 255u);
            const float jy1 = sy1[kj], jx1 = sx1[kj], jy2 = sy2[kj], jx2 = sx2[kj];
            const float a1 = (jy2 - jy1) * (jx2 - jx1);
            (void)j;
#pragma unroll
            for (int q = 0; q < 8; q++) {
                const float ty = fmaxf(jy1, y1[q]), tx = fmaxf(jx1, x1[q]);
                const float by = fminf(jy2, y2[q]), bx = fminf(jx2, x2[q]);
                const float ih = fmaxf(by - ty, 0.f), iw = fmaxf(bx - tx, 0.f);
                const float inter = ih * iw;
                const float iou = inter / ((a1 + a2[q]) - inter);  // exact fp32 div
                if (((live >> q) & 1u) && (iou > 0.7f)) live &= ~(1u << q);
            }
            if (tid == 0) {
                float4 ob = {jy1, jx1, jy2, jx2};
                *(float4*)&outp[it * 4] = ob;
            }
        } else if (tid == 0) {
            const float4 zb = {0.f, 0.f, 0.f, 0.f};
            *(float4*)&outp[it * 4] = zb;
        }
        // parity double-buffer on sRedP -> next iteration's writes are safe
    }
}

// ---------------------------------------------------------------------------
extern "C" void kernel_launch(void* const* d_in, const int* in_sizes, int n_in,
                              void* d_out, int out_size, void* d_ws, size_t ws_size,
                              hipStream_t stream)
{
    const float* feat  = (const float*)d_in[1];
    const float* wconv = (const float*)d_in[2];
    const float* bconv = (const float*)d_in[3];
    const float* wsc   = (const float*)d_in[4];
    const float* bsc   = (const float*)d_in[5];
    const float* wlc   = (const float*)d_in[6];
    const float* blc   = (const float*)d_in[7];
    float* out = (float*)d_out;

    char* ws = (char*)d_ws;
    float*    h     = (float*)(ws);                   // 33,554,432 B
    float*    wt3   = (float*)(ws + 33554432);        //  2,359,296 B
    float*    rois  = (float*)(ws + 35913728);        //  4,718,592 B
    unsigned* keys  = (unsigned*)(ws + 40632320);     //  1,179,648 B
    float*    bk    = (float*)(ws + 41811968);        //    262,144 B
    unsigned* tkey  = (unsigned*)(ws + 42074112);     //     65,536 B
    unsigned* ghist = (unsigned*)(ws + 42139648);     //     65,536 B (total ~42.2 MB)

    prep_wt3       <<<dim3(768),  dim3(256),  0, stream>>>(wconv, wt3, ghist);
    conv3x3_relu_v5<<<dim3(2048), dim3(256),  0, stream>>>(feat, wt3, bconv, h);
    head_decode    <<<dim3(512),  dim3(256),  0, stream>>>(h, wsc, bsc, wlc, blc, keys, rois, ghist);
    topk_sort      <<<dim3(8),    dim3(1024), 0, stream>>>(keys, rois, ghist, bk, tkey);
    nms_reg        <<<dim3(8),    dim3(256),  0, stream>>>(bk, tkey, out);
}